// Round 15
// baseline (232.923 us; speedup 1.0000x reference)
//
#include <hip/hip_runtime.h>
#include <hip/hip_bf16.h>
#include <stdint.h>

typedef __attribute__((ext_vector_type(8))) short short8v;
typedef __attribute__((ext_vector_type(4))) float f32x4;

__device__ __forceinline__ unsigned short f2bf(float f) {
  unsigned int u = __float_as_uint(f);
  u += 0x7fffu + ((u >> 16) & 1u);
  return (unsigned short)(u >> 16);
}
__device__ __forceinline__ unsigned int pack2bf(float a, float b) {
  return (unsigned int)f2bf(a) | ((unsigned int)f2bf(b) << 16);
}
__device__ __forceinline__ float bf_lo(unsigned int v) { return __uint_as_float(v << 16); }
__device__ __forceinline__ float bf_hi(unsigned int v) { return __uint_as_float(v & 0xffff0000u); }

// ---- fused: zero deg+cursor AND build fragment-ordered bf16 W ----
// Wfrag[((ct*4+kt)*64 + lane)*8 + j] = bf16(W[k][col]),
// col = ct*16 + (lane&15), k = kt*32 + 4*(lane>>4) + (j&3) + 16*(j>>2).
__global__ void k_prep(uint4* __restrict__ zp, int n16,
                       const float* __restrict__ W, unsigned short* __restrict__ Wfrag) {
  int b = blockIdx.x;
  if (b < 64) {
    int t = b * 256 + threadIdx.x;  // 0..16383
    int j = t & 7;
    int lane = (t >> 3) & 63;
    int ktct = t >> 9;
    int kt = ktct & 3, ct = ktct >> 2;
    int col = ct * 16 + (lane & 15);
    int k = kt * 32 + 4 * (lane >> 4) + (j & 3) + 16 * (j >> 2);
    Wfrag[t] = f2bf(W[k * 128 + col]);
  } else {
    int i = (b - 64) * 256 + threadIdx.x;
    if (i < n16) {
      uint4 z; z.x = z.y = z.z = z.w = 0u;
      zp[i] = z;
    }
  }
}

// ---- CSR build ----
__global__ void k_count(const int* __restrict__ dst, int* deg, int E) {
  int e = blockIdx.x * blockDim.x + threadIdx.x;
  if (e < E) atomicAdd(&deg[dst[e]], 1);
}

__global__ void k_blocksum(const int* __restrict__ deg, int* partials, float* dis, int N) {
  __shared__ int s[256];
  int t = threadIdx.x;
  int i = blockIdx.x * 256 + t;
  int c = (i < N) ? deg[i] : 0;
  if (i < N) dis[i] = rsqrtf((float)(c + 1));
  s[t] = c;
  __syncthreads();
  for (int off = 128; off > 0; off >>= 1) {
    if (t < off) s[t] += s[t + off];
    __syncthreads();
  }
  if (t == 0) partials[blockIdx.x] = s[0];
}

// scan of this block's deg + prefix over earlier blocks' partials (fused)
__global__ void k_scan_final2(const int* __restrict__ deg, const int* __restrict__ partials,
                              int* csr_off, int N, int E) {
  __shared__ int s[256];
  __shared__ int base;
  int t = threadIdx.x;
  int accp = 0;
  for (int j = t; j < blockIdx.x; j += 256) accp += partials[j];
  s[t] = accp;
  __syncthreads();
  for (int off = 128; off > 0; off >>= 1) {
    if (t < off) s[t] += s[t + off];
    __syncthreads();
  }
  if (t == 0) base = s[0];
  __syncthreads();
  int i = blockIdx.x * 256 + t;
  int c = (i < N) ? deg[i] : 0;
  s[t] = c;
  __syncthreads();
  for (int off = 1; off < 256; off <<= 1) {
    int v = (t >= off) ? s[t - off] : 0;
    __syncthreads();
    s[t] += v;
    __syncthreads();
  }
  if (i < N) csr_off[i] = base + s[t] - c;  // exclusive
  if (i == 0) csr_off[N] = E;
}

__global__ void k_fill(const int* __restrict__ src, const int* __restrict__ dst,
                       const int* __restrict__ csr_off, int* cursor, int* csr_src, int E) {
  int e = blockIdx.x * blockDim.x + threadIdx.x;
  if (e < E) {
    int d = dst[e];
    int p = atomicAdd(&cursor[d], 1);
    csr_src[csr_off[d] + p] = src[e];
  }
}

__device__ __forceinline__ short8v pack8(f32x4 a, f32x4 b) {
  short8v r;
  r[0] = (short)f2bf(a[0]); r[1] = (short)f2bf(a[1]);
  r[2] = (short)f2bf(a[2]); r[3] = (short)f2bf(a[3]);
  r[4] = (short)f2bf(b[0]); r[5] = (short)f2bf(b[1]);
  r[6] = (short)f2bf(b[2]); r[7] = (short)f2bf(b[3]);
  return r;
}

// ---- GEMM: W fully in registers, no LDS/barriers; wave-independent 16-row
// tiles, ping-pong prefetch; shuffle-combined full-line uint4 stores.
// hs[row,:] = bf16(dis[row] * (X[row,:] @ W)).
// launch_bounds(256,4): cap 128 VGPR (measured 124) -> 4 waves/SIMD resident.

#define GLOAD(XB, DD, TT, HAS)                                                  \
  do {                                                                          \
    if (HAS) {                                                                  \
      int row_ = (TT) * 16 + lr;                                                \
      if (row_ < N) {                                                           \
        const float* xp_ = X + (size_t)row_ * 128 + 4 * lg;                     \
        _Pragma("unroll") for (int q = 0; q < 4; ++q) {                         \
          XB[2 * q]     = *(const f32x4*)(xp_ + q * 32);                        \
          XB[2 * q + 1] = *(const f32x4*)(xp_ + q * 32 + 16);                   \
        }                                                                       \
        DD = dis[row_];                                                         \
      } else {                                                                  \
        _Pragma("unroll") for (int q = 0; q < 8; ++q) {                         \
          XB[q][0] = XB[q][1] = XB[q][2] = XB[q][3] = 0.f;                      \
        }                                                                       \
        DD = 0.f;                                                               \
      }                                                                         \
    }                                                                           \
  } while (0)

#define GCOMPUTE(XB, DD, TT)                                                    \
  do {                                                                          \
    short8v afr[4];                                                             \
    _Pragma("unroll") for (int kt = 0; kt < 4; ++kt)                            \
        afr[kt] = pack8(XB[2 * kt], XB[2 * kt + 1]);                            \
    int row_ = (TT) * 16 + lr;                                                  \
    bool wr_ = row_ < N;                                                        \
    unsigned short* hp_ = hs + (size_t)row_ * 128;                              \
    float dd_ = DD;                                                             \
    _Pragma("unroll") for (int cp = 0; cp < 4; ++cp) {                          \
      f32x4 a0 = {0.f, 0.f, 0.f, 0.f}, a1 = {0.f, 0.f, 0.f, 0.f};               \
      _Pragma("unroll") for (int kt = 0; kt < 4; ++kt)                          \
          a0 = __builtin_amdgcn_mfma_f32_16x16x32_bf16(wreg[(2 * cp) * 4 + kt], \
                                                       afr[kt], a0, 0, 0, 0);   \
      _Pragma("unroll") for (int kt = 0; kt < 4; ++kt)                          \
          a1 = __builtin_amdgcn_mfma_f32_16x16x32_bf16(                         \
              wreg[(2 * cp + 1) * 4 + kt], afr[kt], a1, 0, 0, 0);               \
      unsigned int u0x = pack2bf(a0[0] * dd_, a0[1] * dd_);                     \
      unsigned int u0y = pack2bf(a0[2] * dd_, a0[3] * dd_);                     \
      unsigned int u1x = pack2bf(a1[0] * dd_, a1[1] * dd_);                     \
      unsigned int u1y = pack2bf(a1[2] * dd_, a1[3] * dd_);                     \
      int s_ = lg & 1;                                                          \
      unsigned int sx = s_ ? u0x : u1x, sy = s_ ? u0y : u1y;                    \
      unsigned int rx = (unsigned int)__shfl_xor((int)sx, 16);                  \
      unsigned int ry = (unsigned int)__shfl_xor((int)sy, 16);                  \
      uint4 uu;                                                                 \
      if (s_ == 0) { uu.x = u0x; uu.y = u0y; uu.z = rx; uu.w = ry; }            \
      else         { uu.x = rx; uu.y = ry; uu.z = u1x; uu.w = u1y; }            \
      int cb = (s_ ? (2 * cp + 1) : (2 * cp)) * 16 + 8 * (lg >> 1);             \
      if (wr_) *(uint4*)(hp_ + cb) = uu;                                        \
    }                                                                           \
  } while (0)

__global__ __launch_bounds__(256, 4) void k_gemm5(const float* __restrict__ X,
     const unsigned short* __restrict__ Wfrag, const float* __restrict__ dis,
     unsigned short* __restrict__ hs, int N, int ntile) {
  int lane = threadIdx.x & 63;
  int gw = (blockIdx.x * blockDim.x + threadIdx.x) >> 6;
  int nw = (gridDim.x * blockDim.x) >> 6;
  int lr = lane & 15, lg = lane >> 4;

  short8v wreg[32];   // full 128x128 bf16 W, fragment layout, 128 VGPRs
  #pragma unroll
  for (int f = 0; f < 32; ++f)
    wreg[f] = *(const short8v*)(Wfrag + (size_t)(f * 64 + lane) * 8);

  int tile = gw;
  if (tile >= ntile) return;

  f32x4 xv[8], nx[8];
  float d0 = 0.f, d1 = 0.f;
  GLOAD(xv, d0, tile, true);

  for (;;) {
    int t1 = tile + nw;
    bool h1 = t1 < ntile;
    GLOAD(nx, d1, t1, h1);
    GCOMPUTE(xv, d0, tile);
    if (!h1) break;
    int t2 = t1 + nw;
    bool h2 = t2 < ntile;
    GLOAD(xv, d0, t2, h2);
    GCOMPUTE(nx, d1, t1);
    if (!h2) break;
    tile = t2;
  }
}

// ---- aggregation: out[i] = dis[i]*(hs[i] + sum_{s in N(i)} hs[s]) + b ----
// 16 lanes per node; lane owns 16B (8 channels) of the 256B bf16 row.
// out stores are nontemporal (round-13 verified win).
__device__ __forceinline__ void acc8(float* a, uint4 g) {
  a[0] += bf_lo(g.x); a[1] += bf_hi(g.x);
  a[2] += bf_lo(g.y); a[3] += bf_hi(g.y);
  a[4] += bf_lo(g.z); a[5] += bf_hi(g.z);
  a[6] += bf_lo(g.w); a[7] += bf_hi(g.w);
}

__global__ __launch_bounds__(256) void k_agg2(const unsigned short* __restrict__ hs_,
     const int* __restrict__ csr_src, const int* __restrict__ csr_off,
     const float* __restrict__ dis, const float* __restrict__ bias,
     float* __restrict__ out, int N) {
  const uint4* hs = (const uint4*)hs_;
  int lane = threadIdx.x & 63;
  int c = lane & 15;
  int base = lane & 48;  // group base within wave
  int gid = (blockIdx.x * blockDim.x + threadIdx.x) >> 4;
  int G = (gridDim.x * blockDim.x) >> 4;
  int i0 = (int)(((long long)gid * N) / G);
  int i1 = (int)(((long long)(gid + 1) * N) / G);
  if (i0 >= i1) return;
  float4 bA = ((const float4*)bias)[c * 2];
  float4 bB = ((const float4*)bias)[c * 2 + 1];
  int e1prev = csr_off[i0];
  for (int i = i0; i < i1; ++i) {
    int e0 = e1prev;
    int e1 = csr_off[i + 1];
    e1prev = e1;
    float a[8];
    uint4 sv = hs[(size_t)i * 16 + c];
    a[0] = bf_lo(sv.x); a[1] = bf_hi(sv.x);
    a[2] = bf_lo(sv.y); a[3] = bf_hi(sv.y);
    a[4] = bf_lo(sv.z); a[5] = bf_hi(sv.z);
    a[6] = bf_lo(sv.w); a[7] = bf_hi(sv.w);
    int e = e0;
    while (e < e1) {
      int p = e + c;
      int myidx = (p < e1) ? csr_src[p] : 0;
      int kb = (e1 - e < 16) ? (e1 - e) : 16;
      int k = 0;
      for (; k + 8 <= kb; k += 8) {
        int s[8];
        #pragma unroll
        for (int q = 0; q < 8; ++q) s[q] = __shfl(myidx, base + k + q);
        uint4 g[8];
        #pragma unroll
        for (int q = 0; q < 8; ++q) g[q] = hs[(size_t)s[q] * 16 + c];
        #pragma unroll
        for (int q = 0; q < 8; ++q) acc8(a, g[q]);
      }
      for (; k < kb; k += 4) {
        int s0 = __shfl(myidx, base + k);
        int s1 = __shfl(myidx, base + k + 1);
        int s2 = __shfl(myidx, base + k + 2);
        int s3 = __shfl(myidx, base + k + 3);
        bool v1 = (k + 1 < kb), v2 = (k + 2 < kb), v3 = (k + 3 < kb);
        uint4 g0 = hs[(size_t)s0 * 16 + c];
        uint4 g1 = hs[(size_t)(v1 ? s1 : i) * 16 + c];
        uint4 g2 = hs[(size_t)(v2 ? s2 : i) * 16 + c];
        uint4 g3 = hs[(size_t)(v3 ? s3 : i) * 16 + c];
        if (!v1) { g1.x = g1.y = g1.z = g1.w = 0u; }
        if (!v2) { g2.x = g2.y = g2.z = g2.w = 0u; }
        if (!v3) { g3.x = g3.y = g3.z = g3.w = 0u; }
        acc8(a, g0); acc8(a, g1); acc8(a, g2); acc8(a, g3);
      }
      e += kb;
    }
    float di = dis[i];
    f32x4 o0, o1;
    o0[0] = fmaf(di, a[0], bA.x); o0[1] = fmaf(di, a[1], bA.y);
    o0[2] = fmaf(di, a[2], bA.z); o0[3] = fmaf(di, a[3], bA.w);
    o1[0] = fmaf(di, a[4], bB.x); o1[1] = fmaf(di, a[5], bB.y);
    o1[2] = fmaf(di, a[6], bB.z); o1[3] = fmaf(di, a[7], bB.w);
    f32x4* op = (f32x4*)(out + (size_t)i * 128);
    __builtin_nontemporal_store(o0, op + c * 2);
    __builtin_nontemporal_store(o1, op + c * 2 + 1);
  }
}

extern "C" void kernel_launch(void* const* d_in, const int* in_sizes, int n_in,
                              void* d_out, int out_size, void* d_ws, size_t ws_size,
                              hipStream_t stream) {
  const float* X    = (const float*)d_in[0];
  const int*   edge = (const int*)d_in[1];
  const float* W    = (const float*)d_in[2];
  const float* bias = (const float*)d_in[3];
  float* out = (float*)d_out;
  int N = in_sizes[0] / 128;
  int E = in_sizes[1] / 2;
  const int* srcArr = edge;
  const int* dstArr = edge + E;

  char* w = (char*)d_ws;
  auto align = [](size_t x) { return (x + 255) & ~(size_t)255; };
  size_t o = 0;
  int*   deg      = (int*)(w + o);   o += align((size_t)N * 4);
  int*   cursor   = (int*)(w + o);   o += align((size_t)N * 4);
  float* dis      = (float*)(w + o); o += align((size_t)N * 4);
  int*   csr_off  = (int*)(w + o);   o += align(((size_t)N + 1) * 4);
  int*   csr_src  = (int*)(w + o);   o += align((size_t)E * 4);
  int*   partials = (int*)(w + o);   o += align((size_t)4096 * 4);
  unsigned short* Wfrag = (unsigned short*)(w + o); o += align((size_t)16384 * 2);
  unsigned short* hs    = (unsigned short*)(w + o);

  int nbN = (N + 255) / 256;
  int nbE = (E + 255) / 256;
  int ntile = (N + 15) / 16;

  size_t zbytes = align((size_t)N * 4) + align((size_t)N * 4);
  int n16 = (int)(zbytes / 16);
  k_prep<<<64 + (n16 + 255) / 256, 256, 0, stream>>>((uint4*)deg, n16, W, Wfrag);
  k_count<<<nbE, 256, 0, stream>>>(dstArr, deg, E);
  k_blocksum<<<nbN, 256, 0, stream>>>(deg, partials, dis, N);
  k_scan_final2<<<nbN, 256, 0, stream>>>(deg, partials, csr_off, N, E);
  k_fill<<<nbE, 256, 0, stream>>>(srcArr, dstArr, csr_off, cursor, csr_src, E);
  k_gemm5<<<1024, 256, 0, stream>>>(X, Wfrag, dis, hs, N, ntile);
  k_agg2<<<4096, 256, 0, stream>>>(hs, csr_src, csr_off, dis, bias, out, N);
}

// Round 16
// 153.400 us; speedup vs baseline: 1.5184x; 1.5184x over previous
//
#include <hip/hip_runtime.h>
#include <hip/hip_bf16.h>
#include <stdint.h>

typedef __attribute__((ext_vector_type(8))) short short8v;
typedef __attribute__((ext_vector_type(4))) float f32x4;

__device__ __forceinline__ unsigned short f2bf(float f) {
  unsigned int u = __float_as_uint(f);
  u += 0x7fffu + ((u >> 16) & 1u);
  return (unsigned short)(u >> 16);
}
__device__ __forceinline__ unsigned int pack2bf(float a, float b) {
  return (unsigned int)f2bf(a) | ((unsigned int)f2bf(b) << 16);
}
__device__ __forceinline__ float bf_lo(unsigned int v) { return __uint_as_float(v << 16); }
__device__ __forceinline__ float bf_hi(unsigned int v) { return __uint_as_float(v & 0xffff0000u); }

// ---- fused: zero deg+cursor AND build fragment-ordered bf16 W ----
// Wfrag[((ct*4+kt)*64 + lane)*8 + j] = bf16(W[k][col]),
// col = ct*16 + (lane&15), k = kt*32 + 4*(lane>>4) + (j&3) + 16*(j>>2).
__global__ void k_prep(uint4* __restrict__ zp, int n16,
                       const float* __restrict__ W, unsigned short* __restrict__ Wfrag) {
  int b = blockIdx.x;
  if (b < 64) {
    int t = b * 256 + threadIdx.x;  // 0..16383
    int j = t & 7;
    int lane = (t >> 3) & 63;
    int ktct = t >> 9;
    int kt = ktct & 3, ct = ktct >> 2;
    int col = ct * 16 + (lane & 15);
    int k = kt * 32 + 4 * (lane >> 4) + (j & 3) + 16 * (j >> 2);
    Wfrag[t] = f2bf(W[k * 128 + col]);
  } else {
    int i = (b - 64) * 256 + threadIdx.x;
    if (i < n16) {
      uint4 z; z.x = z.y = z.z = z.w = 0u;
      zp[i] = z;
    }
  }
}

// ---- CSR build ----
__global__ void k_count(const int* __restrict__ dst, int* deg, int E) {
  int e = blockIdx.x * blockDim.x + threadIdx.x;
  if (e < E) atomicAdd(&deg[dst[e]], 1);
}

__global__ void k_blocksum(const int* __restrict__ deg, int* partials, float* dis, int N) {
  __shared__ int s[256];
  int t = threadIdx.x;
  int i = blockIdx.x * 256 + t;
  int c = (i < N) ? deg[i] : 0;
  if (i < N) dis[i] = rsqrtf((float)(c + 1));
  s[t] = c;
  __syncthreads();
  for (int off = 128; off > 0; off >>= 1) {
    if (t < off) s[t] += s[t + off];
    __syncthreads();
  }
  if (t == 0) partials[blockIdx.x] = s[0];
}

// scan of this block's deg + prefix over earlier blocks' partials (fused)
__global__ void k_scan_final2(const int* __restrict__ deg, const int* __restrict__ partials,
                              int* csr_off, int N, int E) {
  __shared__ int s[256];
  __shared__ int base;
  int t = threadIdx.x;
  int accp = 0;
  for (int j = t; j < blockIdx.x; j += 256) accp += partials[j];
  s[t] = accp;
  __syncthreads();
  for (int off = 128; off > 0; off >>= 1) {
    if (t < off) s[t] += s[t + off];
    __syncthreads();
  }
  if (t == 0) base = s[0];
  __syncthreads();
  int i = blockIdx.x * 256 + t;
  int c = (i < N) ? deg[i] : 0;
  s[t] = c;
  __syncthreads();
  for (int off = 1; off < 256; off <<= 1) {
    int v = (t >= off) ? s[t - off] : 0;
    __syncthreads();
    s[t] += v;
    __syncthreads();
  }
  if (i < N) csr_off[i] = base + s[t] - c;  // exclusive
  if (i == 0) csr_off[N] = E;
}

__global__ void k_fill(const int* __restrict__ src, const int* __restrict__ dst,
                       const int* __restrict__ csr_off, int* cursor, int* csr_src, int E) {
  int e = blockIdx.x * blockDim.x + threadIdx.x;
  if (e < E) {
    int d = dst[e];
    int p = atomicAdd(&cursor[d], 1);
    csr_src[csr_off[d] + p] = src[e];
  }
}

__device__ __forceinline__ short8v pack8(f32x4 a, f32x4 b) {
  short8v r;
  r[0] = (short)f2bf(a[0]); r[1] = (short)f2bf(a[1]);
  r[2] = (short)f2bf(a[2]); r[3] = (short)f2bf(a[3]);
  r[4] = (short)f2bf(b[0]); r[5] = (short)f2bf(b[1]);
  r[6] = (short)f2bf(b[2]); r[7] = (short)f2bf(b[3]);
  return r;
}

// ---- GEMM: W fully in registers, no LDS/barriers; wave-independent 16-row
// tiles, ping-pong prefetch; shuffle-combined full-line uint4 stores.
// hs[row,:] = bf16(dis[row] * (X[row,:] @ W)).
// launch_bounds(256,2) -> 124 VGPR codegen (no spill); grid 1024 -> 4 waves/SIMD.

#define GLOAD(XB, DD, TT, HAS)                                                  \
  do {                                                                          \
    if (HAS) {                                                                  \
      int row_ = (TT) * 16 + lr;                                                \
      if (row_ < N) {                                                           \
        const float* xp_ = X + (size_t)row_ * 128 + 4 * lg;                     \
        _Pragma("unroll") for (int q = 0; q < 4; ++q) {                         \
          XB[2 * q]     = *(const f32x4*)(xp_ + q * 32);                        \
          XB[2 * q + 1] = *(const f32x4*)(xp_ + q * 32 + 16);                   \
        }                                                                       \
        DD = dis[row_];                                                         \
      } else {                                                                  \
        _Pragma("unroll") for (int q = 0; q < 8; ++q) {                         \
          XB[q][0] = XB[q][1] = XB[q][2] = XB[q][3] = 0.f;                      \
        }                                                                       \
        DD = 0.f;                                                               \
      }                                                                         \
    }                                                                           \
  } while (0)

#define GCOMPUTE(XB, DD, TT)                                                    \
  do {                                                                          \
    short8v afr[4];                                                             \
    _Pragma("unroll") for (int kt = 0; kt < 4; ++kt)                            \
        afr[kt] = pack8(XB[2 * kt], XB[2 * kt + 1]);                            \
    int row_ = (TT) * 16 + lr;                                                  \
    bool wr_ = row_ < N;                                                        \
    unsigned short* hp_ = hs + (size_t)row_ * 128;                              \
    float dd_ = DD;                                                             \
    _Pragma("unroll") for (int cp = 0; cp < 4; ++cp) {                          \
      f32x4 a0 = {0.f, 0.f, 0.f, 0.f}, a1 = {0.f, 0.f, 0.f, 0.f};               \
      _Pragma("unroll") for (int kt = 0; kt < 4; ++kt)                          \
          a0 = __builtin_amdgcn_mfma_f32_16x16x32_bf16(wreg[(2 * cp) * 4 + kt], \
                                                       afr[kt], a0, 0, 0, 0);   \
      _Pragma("unroll") for (int kt = 0; kt < 4; ++kt)                          \
          a1 = __builtin_amdgcn_mfma_f32_16x16x32_bf16(                         \
              wreg[(2 * cp + 1) * 4 + kt], afr[kt], a1, 0, 0, 0);               \
      unsigned int u0x = pack2bf(a0[0] * dd_, a0[1] * dd_);                     \
      unsigned int u0y = pack2bf(a0[2] * dd_, a0[3] * dd_);                     \
      unsigned int u1x = pack2bf(a1[0] * dd_, a1[1] * dd_);                     \
      unsigned int u1y = pack2bf(a1[2] * dd_, a1[3] * dd_);                     \
      int s_ = lg & 1;                                                          \
      unsigned int sx = s_ ? u0x : u1x, sy = s_ ? u0y : u1y;                    \
      unsigned int rx = (unsigned int)__shfl_xor((int)sx, 16);                  \
      unsigned int ry = (unsigned int)__shfl_xor((int)sy, 16);                  \
      uint4 uu;                                                                 \
      if (s_ == 0) { uu.x = u0x; uu.y = u0y; uu.z = rx; uu.w = ry; }            \
      else         { uu.x = rx; uu.y = ry; uu.z = u1x; uu.w = u1y; }            \
      int cb = (s_ ? (2 * cp + 1) : (2 * cp)) * 16 + 8 * (lg >> 1);             \
      if (wr_) *(uint4*)(hp_ + cb) = uu;                                        \
    }                                                                           \
  } while (0)

__global__ __launch_bounds__(256, 2) void k_gemm5(const float* __restrict__ X,
     const unsigned short* __restrict__ Wfrag, const float* __restrict__ dis,
     unsigned short* __restrict__ hs, int N, int ntile) {
  int lane = threadIdx.x & 63;
  int gw = (blockIdx.x * blockDim.x + threadIdx.x) >> 6;
  int nw = (gridDim.x * blockDim.x) >> 6;
  int lr = lane & 15, lg = lane >> 4;

  short8v wreg[32];   // full 128x128 bf16 W, fragment layout, 128 VGPRs
  #pragma unroll
  for (int f = 0; f < 32; ++f)
    wreg[f] = *(const short8v*)(Wfrag + (size_t)(f * 64 + lane) * 8);

  int tile = gw;
  if (tile >= ntile) return;

  f32x4 xv[8], nx[8];
  float d0 = 0.f, d1 = 0.f;
  GLOAD(xv, d0, tile, true);

  for (;;) {
    int t1 = tile + nw;
    bool h1 = t1 < ntile;
    GLOAD(nx, d1, t1, h1);
    GCOMPUTE(xv, d0, tile);
    if (!h1) break;
    int t2 = t1 + nw;
    bool h2 = t2 < ntile;
    GLOAD(xv, d0, t2, h2);
    GCOMPUTE(nx, d1, t1);
    if (!h2) break;
    tile = t2;
  }
}

// ---- aggregation: out[i] = dis[i]*(hs[i] + sum_{s in N(i)} hs[s]) + b ----
// 16 lanes per node; lane owns 16B (8 channels) of the 256B bf16 row.
// out stores are nontemporal (round-13 verified win).
__device__ __forceinline__ void acc8(float* a, uint4 g) {
  a[0] += bf_lo(g.x); a[1] += bf_hi(g.x);
  a[2] += bf_lo(g.y); a[3] += bf_hi(g.y);
  a[4] += bf_lo(g.z); a[5] += bf_hi(g.z);
  a[6] += bf_lo(g.w); a[7] += bf_hi(g.w);
}

__global__ __launch_bounds__(256) void k_agg2(const unsigned short* __restrict__ hs_,
     const int* __restrict__ csr_src, const int* __restrict__ csr_off,
     const float* __restrict__ dis, const float* __restrict__ bias,
     float* __restrict__ out, int N) {
  const uint4* hs = (const uint4*)hs_;
  int lane = threadIdx.x & 63;
  int c = lane & 15;
  int base = lane & 48;  // group base within wave
  int gid = (blockIdx.x * blockDim.x + threadIdx.x) >> 4;
  int G = (gridDim.x * blockDim.x) >> 4;
  int i0 = (int)(((long long)gid * N) / G);
  int i1 = (int)(((long long)(gid + 1) * N) / G);
  if (i0 >= i1) return;
  float4 bA = ((const float4*)bias)[c * 2];
  float4 bB = ((const float4*)bias)[c * 2 + 1];
  int e1prev = csr_off[i0];
  for (int i = i0; i < i1; ++i) {
    int e0 = e1prev;
    int e1 = csr_off[i + 1];
    e1prev = e1;
    float a[8];
    uint4 sv = hs[(size_t)i * 16 + c];
    a[0] = bf_lo(sv.x); a[1] = bf_hi(sv.x);
    a[2] = bf_lo(sv.y); a[3] = bf_hi(sv.y);
    a[4] = bf_lo(sv.z); a[5] = bf_hi(sv.z);
    a[6] = bf_lo(sv.w); a[7] = bf_hi(sv.w);
    int e = e0;
    while (e < e1) {
      int p = e + c;
      int myidx = (p < e1) ? csr_src[p] : 0;
      int kb = (e1 - e < 16) ? (e1 - e) : 16;
      int k = 0;
      for (; k + 8 <= kb; k += 8) {
        int s[8];
        #pragma unroll
        for (int q = 0; q < 8; ++q) s[q] = __shfl(myidx, base + k + q);
        uint4 g[8];
        #pragma unroll
        for (int q = 0; q < 8; ++q) g[q] = hs[(size_t)s[q] * 16 + c];
        #pragma unroll
        for (int q = 0; q < 8; ++q) acc8(a, g[q]);
      }
      for (; k < kb; k += 4) {
        int s0 = __shfl(myidx, base + k);
        int s1 = __shfl(myidx, base + k + 1);
        int s2 = __shfl(myidx, base + k + 2);
        int s3 = __shfl(myidx, base + k + 3);
        bool v1 = (k + 1 < kb), v2 = (k + 2 < kb), v3 = (k + 3 < kb);
        uint4 g0 = hs[(size_t)s0 * 16 + c];
        uint4 g1 = hs[(size_t)(v1 ? s1 : i) * 16 + c];
        uint4 g2 = hs[(size_t)(v2 ? s2 : i) * 16 + c];
        uint4 g3 = hs[(size_t)(v3 ? s3 : i) * 16 + c];
        if (!v1) { g1.x = g1.y = g1.z = g1.w = 0u; }
        if (!v2) { g2.x = g2.y = g2.z = g2.w = 0u; }
        if (!v3) { g3.x = g3.y = g3.z = g3.w = 0u; }
        acc8(a, g0); acc8(a, g1); acc8(a, g2); acc8(a, g3);
      }
      e += kb;
    }
    float di = dis[i];
    f32x4 o0, o1;
    o0[0] = fmaf(di, a[0], bA.x); o0[1] = fmaf(di, a[1], bA.y);
    o0[2] = fmaf(di, a[2], bA.z); o0[3] = fmaf(di, a[3], bA.w);
    o1[0] = fmaf(di, a[4], bB.x); o1[1] = fmaf(di, a[5], bB.y);
    o1[2] = fmaf(di, a[6], bB.z); o1[3] = fmaf(di, a[7], bB.w);
    f32x4* op = (f32x4*)(out + (size_t)i * 128);
    __builtin_nontemporal_store(o0, op + c * 2);
    __builtin_nontemporal_store(o1, op + c * 2 + 1);
  }
}

extern "C" void kernel_launch(void* const* d_in, const int* in_sizes, int n_in,
                              void* d_out, int out_size, void* d_ws, size_t ws_size,
                              hipStream_t stream) {
  const float* X    = (const float*)d_in[0];
  const int*   edge = (const int*)d_in[1];
  const float* W    = (const float*)d_in[2];
  const float* bias = (const float*)d_in[3];
  float* out = (float*)d_out;
  int N = in_sizes[0] / 128;
  int E = in_sizes[1] / 2;
  const int* srcArr = edge;
  const int* dstArr = edge + E;

  char* w = (char*)d_ws;
  auto align = [](size_t x) { return (x + 255) & ~(size_t)255; };
  size_t o = 0;
  int*   deg      = (int*)(w + o);   o += align((size_t)N * 4);
  int*   cursor   = (int*)(w + o);   o += align((size_t)N * 4);
  float* dis      = (float*)(w + o); o += align((size_t)N * 4);
  int*   csr_off  = (int*)(w + o);   o += align(((size_t)N + 1) * 4);
  int*   csr_src  = (int*)(w + o);   o += align((size_t)E * 4);
  int*   partials = (int*)(w + o);   o += align((size_t)4096 * 4);
  unsigned short* Wfrag = (unsigned short*)(w + o); o += align((size_t)16384 * 2);
  unsigned short* hs    = (unsigned short*)(w + o);

  int nbN = (N + 255) / 256;
  int nbE = (E + 255) / 256;
  int ntile = (N + 15) / 16;

  size_t zbytes = align((size_t)N * 4) + align((size_t)N * 4);
  int n16 = (int)(zbytes / 16);
  k_prep<<<64 + (n16 + 255) / 256, 256, 0, stream>>>((uint4*)deg, n16, W, Wfrag);
  k_count<<<nbE, 256, 0, stream>>>(dstArr, deg, E);
  k_blocksum<<<nbN, 256, 0, stream>>>(deg, partials, dis, N);
  k_scan_final2<<<nbN, 256, 0, stream>>>(deg, partials, csr_off, N, E);
  k_fill<<<nbE, 256, 0, stream>>>(srcArr, dstArr, csr_off, cursor, csr_src, E);
  k_gemm5<<<1024, 256, 0, stream>>>(X, Wfrag, dis, hs, N, ntile);
  k_agg2<<<4096, 256, 0, stream>>>(hs, csr_src, csr_off, dis, bias, out, N);
}

// Round 17
// 147.586 us; speedup vs baseline: 1.5782x; 1.0394x over previous
//
#include <hip/hip_runtime.h>
#include <hip/hip_bf16.h>
#include <stdint.h>

typedef __attribute__((ext_vector_type(8))) short short8v;
typedef __attribute__((ext_vector_type(4))) float f32x4;

__device__ __forceinline__ unsigned short f2bf(float f) {
  unsigned int u = __float_as_uint(f);
  u += 0x7fffu + ((u >> 16) & 1u);
  return (unsigned short)(u >> 16);
}
__device__ __forceinline__ unsigned int pack2bf(float a, float b) {
  return (unsigned int)f2bf(a) | ((unsigned int)f2bf(b) << 16);
}
__device__ __forceinline__ float bf_lo(unsigned int v) { return __uint_as_float(v << 16); }
__device__ __forceinline__ float bf_hi(unsigned int v) { return __uint_as_float(v & 0xffff0000u); }

// ---- fused: zero deg+cursor AND build fragment-ordered bf16 W ----
// Wfrag[((ct*4+kt)*64 + lane)*8 + j] = bf16(W[k][col]),
// col = ct*16 + (lane&15), k = kt*32 + 4*(lane>>4) + (j&3) + 16*(j>>2).
__global__ void k_prep(uint4* __restrict__ zp, int n16,
                       const float* __restrict__ W, unsigned short* __restrict__ Wfrag) {
  int b = blockIdx.x;
  if (b < 64) {
    int t = b * 256 + threadIdx.x;  // 0..16383
    int j = t & 7;
    int lane = (t >> 3) & 63;
    int ktct = t >> 9;
    int kt = ktct & 3, ct = ktct >> 2;
    int col = ct * 16 + (lane & 15);
    int k = kt * 32 + 4 * (lane >> 4) + (j & 3) + 16 * (j >> 2);
    Wfrag[t] = f2bf(W[k * 128 + col]);
  } else {
    int i = (b - 64) * 256 + threadIdx.x;
    if (i < n16) {
      uint4 z; z.x = z.y = z.z = z.w = 0u;
      zp[i] = z;
    }
  }
}

// ---- CSR build ----
__global__ void k_count(const int* __restrict__ dst, int* deg, int E) {
  int e = blockIdx.x * blockDim.x + threadIdx.x;
  if (e < E) atomicAdd(&deg[dst[e]], 1);
}

__global__ void k_blocksum(const int* __restrict__ deg, int* partials, float* dis, int N) {
  __shared__ int s[256];
  int t = threadIdx.x;
  int i = blockIdx.x * 256 + t;
  int c = (i < N) ? deg[i] : 0;
  if (i < N) dis[i] = rsqrtf((float)(c + 1));
  s[t] = c;
  __syncthreads();
  for (int off = 128; off > 0; off >>= 1) {
    if (t < off) s[t] += s[t + off];
    __syncthreads();
  }
  if (t == 0) partials[blockIdx.x] = s[0];
}

// scan of this block's deg + prefix over earlier blocks' partials (fused)
__global__ void k_scan_final2(const int* __restrict__ deg, const int* __restrict__ partials,
                              int* csr_off, int N, int E) {
  __shared__ int s[256];
  __shared__ int base;
  int t = threadIdx.x;
  int accp = 0;
  for (int j = t; j < blockIdx.x; j += 256) accp += partials[j];
  s[t] = accp;
  __syncthreads();
  for (int off = 128; off > 0; off >>= 1) {
    if (t < off) s[t] += s[t + off];
    __syncthreads();
  }
  if (t == 0) base = s[0];
  __syncthreads();
  int i = blockIdx.x * 256 + t;
  int c = (i < N) ? deg[i] : 0;
  s[t] = c;
  __syncthreads();
  for (int off = 1; off < 256; off <<= 1) {
    int v = (t >= off) ? s[t - off] : 0;
    __syncthreads();
    s[t] += v;
    __syncthreads();
  }
  if (i < N) csr_off[i] = base + s[t] - c;  // exclusive
  if (i == 0) csr_off[N] = E;
}

__global__ void k_fill(const int* __restrict__ src, const int* __restrict__ dst,
                       const int* __restrict__ csr_off, int* cursor, int* csr_src, int E) {
  int e = blockIdx.x * blockDim.x + threadIdx.x;
  if (e < E) {
    int d = dst[e];
    int p = atomicAdd(&cursor[d], 1);
    csr_src[csr_off[d] + p] = src[e];
  }
}

__device__ __forceinline__ short8v pack8(f32x4 a, f32x4 b) {
  short8v r;
  r[0] = (short)f2bf(a[0]); r[1] = (short)f2bf(a[1]);
  r[2] = (short)f2bf(a[2]); r[3] = (short)f2bf(a[3]);
  r[4] = (short)f2bf(b[0]); r[5] = (short)f2bf(b[1]);
  r[6] = (short)f2bf(b[2]); r[7] = (short)f2bf(b[3]);
  return r;
}

// ---- GEMM: W fully in registers, no LDS/barriers; wave-independent 16-row
// tiles, ping-pong prefetch PINNED with sched_barrier(0) so the compiler
// cannot sink the prefetch loads into the next compute (VGPR=124 in r13
// proved it was collapsing the pipeline).
// hs[row,:] = bf16(dis[row] * (X[row,:] @ W)).

#define GLOAD(XB, DD, TT, HAS)                                                  \
  do {                                                                          \
    if (HAS) {                                                                  \
      int row_ = (TT) * 16 + lr;                                                \
      if (row_ < N) {                                                           \
        const float* xp_ = X + (size_t)row_ * 128 + 4 * lg;                     \
        _Pragma("unroll") for (int q = 0; q < 4; ++q) {                         \
          XB[2 * q]     = *(const f32x4*)(xp_ + q * 32);                        \
          XB[2 * q + 1] = *(const f32x4*)(xp_ + q * 32 + 16);                   \
        }                                                                       \
        DD = dis[row_];                                                         \
      } else {                                                                  \
        _Pragma("unroll") for (int q = 0; q < 8; ++q) {                         \
          XB[q][0] = XB[q][1] = XB[q][2] = XB[q][3] = 0.f;                      \
        }                                                                       \
        DD = 0.f;                                                               \
      }                                                                         \
    }                                                                           \
  } while (0)

#define GCOMPUTE(XB, DD, TT)                                                    \
  do {                                                                          \
    short8v afr[4];                                                             \
    _Pragma("unroll") for (int kt = 0; kt < 4; ++kt)                            \
        afr[kt] = pack8(XB[2 * kt], XB[2 * kt + 1]);                            \
    int row_ = (TT) * 16 + lr;                                                  \
    bool wr_ = row_ < N;                                                        \
    unsigned short* hp_ = hs + (size_t)row_ * 128;                              \
    float dd_ = DD;                                                             \
    _Pragma("unroll") for (int cp = 0; cp < 4; ++cp) {                          \
      f32x4 a0 = {0.f, 0.f, 0.f, 0.f}, a1 = {0.f, 0.f, 0.f, 0.f};               \
      _Pragma("unroll") for (int kt = 0; kt < 4; ++kt)                          \
          a0 = __builtin_amdgcn_mfma_f32_16x16x32_bf16(wreg[(2 * cp) * 4 + kt], \
                                                       afr[kt], a0, 0, 0, 0);   \
      _Pragma("unroll") for (int kt = 0; kt < 4; ++kt)                          \
          a1 = __builtin_amdgcn_mfma_f32_16x16x32_bf16(                         \
              wreg[(2 * cp + 1) * 4 + kt], afr[kt], a1, 0, 0, 0);               \
      unsigned int u0x = pack2bf(a0[0] * dd_, a0[1] * dd_);                     \
      unsigned int u0y = pack2bf(a0[2] * dd_, a0[3] * dd_);                     \
      unsigned int u1x = pack2bf(a1[0] * dd_, a1[1] * dd_);                     \
      unsigned int u1y = pack2bf(a1[2] * dd_, a1[3] * dd_);                     \
      int s_ = lg & 1;                                                          \
      unsigned int sx = s_ ? u0x : u1x, sy = s_ ? u0y : u1y;                    \
      unsigned int rx = (unsigned int)__shfl_xor((int)sx, 16);                  \
      unsigned int ry = (unsigned int)__shfl_xor((int)sy, 16);                  \
      uint4 uu;                                                                 \
      if (s_ == 0) { uu.x = u0x; uu.y = u0y; uu.z = rx; uu.w = ry; }            \
      else         { uu.x = rx; uu.y = ry; uu.z = u1x; uu.w = u1y; }            \
      int cb = (s_ ? (2 * cp + 1) : (2 * cp)) * 16 + 8 * (lg >> 1);             \
      if (wr_) *(uint4*)(hp_ + cb) = uu;                                        \
    }                                                                           \
  } while (0)

__global__ __launch_bounds__(256, 2) void k_gemm5(const float* __restrict__ X,
     const unsigned short* __restrict__ Wfrag, const float* __restrict__ dis,
     unsigned short* __restrict__ hs, int N, int ntile) {
  int lane = threadIdx.x & 63;
  int gw = (blockIdx.x * blockDim.x + threadIdx.x) >> 6;
  int nw = (gridDim.x * blockDim.x) >> 6;
  int lr = lane & 15, lg = lane >> 4;

  short8v wreg[32];   // full 128x128 bf16 W, fragment layout, 128 VGPRs
  #pragma unroll
  for (int f = 0; f < 32; ++f)
    wreg[f] = *(const short8v*)(Wfrag + (size_t)(f * 64 + lane) * 8);

  int tile = gw;
  if (tile >= ntile) return;

  f32x4 xv[8], nx[8];
  float d0 = 0.f, d1 = 0.f;
  GLOAD(xv, d0, tile, true);

  for (;;) {
    int t1 = tile + nw;
    bool h1 = t1 < ntile;
    GLOAD(nx, d1, t1, h1);
    __builtin_amdgcn_sched_barrier(0);   // pin: prefetch issues BEFORE compute
    GCOMPUTE(xv, d0, tile);
    if (!h1) break;
    int t2 = t1 + nw;
    bool h2 = t2 < ntile;
    GLOAD(xv, d0, t2, h2);
    __builtin_amdgcn_sched_barrier(0);   // pin: prefetch issues BEFORE compute
    GCOMPUTE(nx, d1, t1);
    if (!h2) break;
    tile = t2;
  }
}

// ---- aggregation: out[i] = dis[i]*(hs[i] + sum_{s in N(i)} hs[s]) + b ----
// 16 lanes per node; lane owns 16B (8 channels) of the 256B bf16 row.
// out stores are nontemporal (round-13 verified win).
__device__ __forceinline__ void acc8(float* a, uint4 g) {
  a[0] += bf_lo(g.x); a[1] += bf_hi(g.x);
  a[2] += bf_lo(g.y); a[3] += bf_hi(g.y);
  a[4] += bf_lo(g.z); a[5] += bf_hi(g.z);
  a[6] += bf_lo(g.w); a[7] += bf_hi(g.w);
}

__global__ __launch_bounds__(256) void k_agg2(const unsigned short* __restrict__ hs_,
     const int* __restrict__ csr_src, const int* __restrict__ csr_off,
     const float* __restrict__ dis, const float* __restrict__ bias,
     float* __restrict__ out, int N) {
  const uint4* hs = (const uint4*)hs_;
  int lane = threadIdx.x & 63;
  int c = lane & 15;
  int base = lane & 48;  // group base within wave
  int gid = (blockIdx.x * blockDim.x + threadIdx.x) >> 4;
  int G = (gridDim.x * blockDim.x) >> 4;
  int i0 = (int)(((long long)gid * N) / G);
  int i1 = (int)(((long long)(gid + 1) * N) / G);
  if (i0 >= i1) return;
  float4 bA = ((const float4*)bias)[c * 2];
  float4 bB = ((const float4*)bias)[c * 2 + 1];
  int e1prev = csr_off[i0];
  for (int i = i0; i < i1; ++i) {
    int e0 = e1prev;
    int e1 = csr_off[i + 1];
    e1prev = e1;
    float a[8];
    uint4 sv = hs[(size_t)i * 16 + c];
    a[0] = bf_lo(sv.x); a[1] = bf_hi(sv.x);
    a[2] = bf_lo(sv.y); a[3] = bf_hi(sv.y);
    a[4] = bf_lo(sv.z); a[5] = bf_hi(sv.z);
    a[6] = bf_lo(sv.w); a[7] = bf_hi(sv.w);
    int e = e0;
    while (e < e1) {
      int p = e + c;
      int myidx = (p < e1) ? csr_src[p] : 0;
      int kb = (e1 - e < 16) ? (e1 - e) : 16;
      int k = 0;
      for (; k + 8 <= kb; k += 8) {
        int s[8];
        #pragma unroll
        for (int q = 0; q < 8; ++q) s[q] = __shfl(myidx, base + k + q);
        uint4 g[8];
        #pragma unroll
        for (int q = 0; q < 8; ++q) g[q] = hs[(size_t)s[q] * 16 + c];
        #pragma unroll
        for (int q = 0; q < 8; ++q) acc8(a, g[q]);
      }
      for (; k < kb; k += 4) {
        int s0 = __shfl(myidx, base + k);
        int s1 = __shfl(myidx, base + k + 1);
        int s2 = __shfl(myidx, base + k + 2);
        int s3 = __shfl(myidx, base + k + 3);
        bool v1 = (k + 1 < kb), v2 = (k + 2 < kb), v3 = (k + 3 < kb);
        uint4 g0 = hs[(size_t)s0 * 16 + c];
        uint4 g1 = hs[(size_t)(v1 ? s1 : i) * 16 + c];
        uint4 g2 = hs[(size_t)(v2 ? s2 : i) * 16 + c];
        uint4 g3 = hs[(size_t)(v3 ? s3 : i) * 16 + c];
        if (!v1) { g1.x = g1.y = g1.z = g1.w = 0u; }
        if (!v2) { g2.x = g2.y = g2.z = g2.w = 0u; }
        if (!v3) { g3.x = g3.y = g3.z = g3.w = 0u; }
        acc8(a, g0); acc8(a, g1); acc8(a, g2); acc8(a, g3);
      }
      e += kb;
    }
    float di = dis[i];
    f32x4 o0, o1;
    o0[0] = fmaf(di, a[0], bA.x); o0[1] = fmaf(di, a[1], bA.y);
    o0[2] = fmaf(di, a[2], bA.z); o0[3] = fmaf(di, a[3], bA.w);
    o1[0] = fmaf(di, a[4], bB.x); o1[1] = fmaf(di, a[5], bB.y);
    o1[2] = fmaf(di, a[6], bB.z); o1[3] = fmaf(di, a[7], bB.w);
    f32x4* op = (f32x4*)(out + (size_t)i * 128);
    __builtin_nontemporal_store(o0, op + c * 2);
    __builtin_nontemporal_store(o1, op + c * 2 + 1);
  }
}

extern "C" void kernel_launch(void* const* d_in, const int* in_sizes, int n_in,
                              void* d_out, int out_size, void* d_ws, size_t ws_size,
                              hipStream_t stream) {
  const float* X    = (const float*)d_in[0];
  const int*   edge = (const int*)d_in[1];
  const float* W    = (const float*)d_in[2];
  const float* bias = (const float*)d_in[3];
  float* out = (float*)d_out;
  int N = in_sizes[0] / 128;
  int E = in_sizes[1] / 2;
  const int* srcArr = edge;
  const int* dstArr = edge + E;

  char* w = (char*)d_ws;
  auto align = [](size_t x) { return (x + 255) & ~(size_t)255; };
  size_t o = 0;
  int*   deg      = (int*)(w + o);   o += align((size_t)N * 4);
  int*   cursor   = (int*)(w + o);   o += align((size_t)N * 4);
  float* dis      = (float*)(w + o); o += align((size_t)N * 4);
  int*   csr_off  = (int*)(w + o);   o += align(((size_t)N + 1) * 4);
  int*   csr_src  = (int*)(w + o);   o += align((size_t)E * 4);
  int*   partials = (int*)(w + o);   o += align((size_t)4096 * 4);
  unsigned short* Wfrag = (unsigned short*)(w + o); o += align((size_t)16384 * 2);
  unsigned short* hs    = (unsigned short*)(w + o);

  int nbN = (N + 255) / 256;
  int nbE = (E + 255) / 256;
  int ntile = (N + 15) / 16;

  size_t zbytes = align((size_t)N * 4) + align((size_t)N * 4);
  int n16 = (int)(zbytes / 16);
  k_prep<<<64 + (n16 + 255) / 256, 256, 0, stream>>>((uint4*)deg, n16, W, Wfrag);
  k_count<<<nbE, 256, 0, stream>>>(dstArr, deg, E);
  k_blocksum<<<nbN, 256, 0, stream>>>(deg, partials, dis, N);
  k_scan_final2<<<nbN, 256, 0, stream>>>(deg, partials, csr_off, N, E);
  k_fill<<<nbE, 256, 0, stream>>>(srcArr, dstArr, csr_off, cursor, csr_src, E);
  k_gemm5<<<512, 256, 0, stream>>>(X, Wfrag, dis, hs, N, ntile);
  k_agg2<<<4096, 256, 0, stream>>>(hs, csr_src, csr_off, dis, bias, out, N);
}